// Round 10
// baseline (100.930 us; speedup 1.0000x reference)
//
#include <hip/hip_runtime.h>

// Problem constants: B=64, Cin=512, Cout=512, H=W=28 (HW=784), K=8 experts.
#define NB 64
#define CIN 512
#define COUT 512
#define HW 784
#define KEXP 8

typedef __attribute__((ext_vector_type(8))) short bf16x8;   // 8 bf16 = 4 VGPR (MFMA A/B frag)
typedef __attribute__((ext_vector_type(4))) float f32x4;    // MFMA C/D frag

typedef const __attribute__((address_space(1))) unsigned int GU32;
typedef __attribute__((address_space(3))) unsigned int LU32;

__device__ __forceinline__ unsigned f2bf1(float f) {
  unsigned u = __builtin_bit_cast(unsigned, f);
  return (u + 0x7FFFu + ((u >> 16) & 1u)) >> 16;   // RNE fp32->bf16
}
__device__ __forceinline__ unsigned f2bf2(float lo, float hi) {
  return f2bf1(lo) | (f2bf1(hi) << 16);
}

// ---------------- Kernel 1: fused transpose(x)->bf16-tiled + pooled parts --
// Grid 7168 = (b*7+nb)*16 + kk. Per block: one 32x112 tile of x[b] ->
//   xt[((b*7+nb)*16+kk)*448 + u], u=kgrp*112+col packs
//   x[b][kk*32+kgrp*8+j][nb*112+col], j=0..7 (k-contiguous bf16x8).
// Plus pooled partials parts[nb][b][kk*32+r] (sum over the 112 cols).
__global__ __launch_bounds__(256) void xtpool_kernel(const float* __restrict__ x,
                                                     uint4* __restrict__ xt,
                                                     float* __restrict__ parts) {
  __shared__ float tile[32][116];
  int id = blockIdx.x;
  int kk = id & 15, bn = id >> 4;
  int b = bn / 7, nb = bn - b * 7;
  const float* xsrc = x + (size_t)b * (CIN * HW) + (size_t)kk * 32 * HW + nb * 112;
  uint4* dst = xt + (size_t)id * 448;
  int t = threadIdx.x;

  // 896 float4 units: u -> row u/28, col4 u%28
  #pragma unroll
  for (int i = 0; i < 4; ++i) {
    int u = t + i * 256;
    if (u < 896) {
      int r = u / 28, c4 = u - r * 28;
      float4 v = ((const float4*)(xsrc + (size_t)r * HW))[c4];
      *(float4*)&tile[r][c4 * 4] = v;
    }
  }
  __syncthreads();

  // pooled partial: row pr, threads pp=0..7 each sum 14 cols, shfl-reduce
  {
    int pr = t >> 3, pp = t & 7;
    float s = 0.f;
    #pragma unroll
    for (int i = 0; i < 14; ++i) s += tile[pr][pp * 14 + i];
    s += __shfl_xor(s, 1); s += __shfl_xor(s, 2); s += __shfl_xor(s, 4);
    if (pp == 0) parts[((size_t)nb * NB + b) * CIN + kk * 32 + pr] = s;
  }

  // pack units (k-contiguous bf16x8), natural slot order
  {
    int k0 = t / 112, c0 = t - k0 * 112;
    uint4 pk;
    pk.x = f2bf2(tile[k0 * 8 + 0][c0], tile[k0 * 8 + 1][c0]);
    pk.y = f2bf2(tile[k0 * 8 + 2][c0], tile[k0 * 8 + 3][c0]);
    pk.z = f2bf2(tile[k0 * 8 + 4][c0], tile[k0 * 8 + 5][c0]);
    pk.w = f2bf2(tile[k0 * 8 + 6][c0], tile[k0 * 8 + 7][c0]);
    dst[t] = pk;
  }
  if (t < 192) {
    int t2 = 256 + t, k1 = t2 / 112, c1 = t2 - k1 * 112;
    uint4 pk;
    pk.x = f2bf2(tile[k1 * 8 + 0][c1], tile[k1 * 8 + 1][c1]);
    pk.y = f2bf2(tile[k1 * 8 + 2][c1], tile[k1 * 8 + 3][c1]);
    pk.z = f2bf2(tile[k1 * 8 + 4][c1], tile[k1 * 8 + 5][c1]);
    pk.w = f2bf2(tile[k1 * 8 + 6][c1], tile[k1 * 8 + 7][c1]);
    dst[256 + t] = pk;
  }
}

// ---------------- Kernel 2: gate (per-batch block) + local sparsemax -------
__global__ __launch_bounds__(256) void gate_kernel(const float* __restrict__ parts,
                                                   const float* __restrict__ gw,
                                                   const float* __restrict__ gb,
                                                   float* __restrict__ g) {
  __shared__ float red[4][KEXP];
  int b = blockIdx.x;
  int t = threadIdx.x;
  int lane = t & 63, w = t >> 6;

  float p0 = 0.f, p1 = 0.f;
  #pragma unroll
  for (int q = 0; q < 7; ++q) {
    const float* pr = parts + (size_t)q * (NB * CIN) + b * CIN;
    p0 += pr[t];
    p1 += pr[t + 256];
  }
  float zk[KEXP];
  #pragma unroll
  for (int k = 0; k < KEXP; ++k)
    zk[k] = p0 * gw[k * CIN + t] + p1 * gw[k * CIN + t + 256];

  #pragma unroll
  for (int k = 0; k < KEXP; ++k) {
    float s = zk[k];
    #pragma unroll
    for (int off = 32; off; off >>= 1) s += __shfl_down(s, off);
    if (lane == 0) red[w][k] = s;
  }
  __syncthreads();

  if (t == 0) {
    float z[8], zs[8];
    #pragma unroll
    for (int j = 0; j < 8; ++j) {
      z[j] = (red[0][j] + red[1][j] + red[2][j] + red[3][j]) * (1.0f / 784.0f) + gb[j];
      zs[j] = z[j];
    }
    #pragma unroll
    for (int a = 1; a < 8; ++a) {
      float v = zs[a]; int j = a;
      while (j > 0 && zs[j - 1] < v) { zs[j] = zs[j - 1]; --j; }
      zs[j] = v;
    }
    float cums[8]; float csum = 0.f;
    #pragma unroll
    for (int j = 0; j < 8; ++j) { csum += zs[j]; cums[j] = csum; }
    int kz = 0;
    #pragma unroll
    for (int j = 0; j < 8; ++j)
      if (1.0f + (float)(j + 1) * zs[j] > cums[j]) kz = j + 1;
    float tau = (cums[kz - 1] - 1.0f) / (float)kz;
    #pragma unroll
    for (int j = 0; j < 8; ++j) g[b * 8 + j] = fmaxf(z[j] - tau, 0.0f);
  }
}

// ---------------- Kernel 3: w_eff builder (bf16, BM=256 GEMM-tiled) -------
// unit(b,o,i) = b*32768 + ((o>>8)*16 + (i>>5))*1024 + ((i>>3)&3)*256 + (o&255)
// Grid dim3(32,4,2): z splits batches (32 each) -> 256 blocks (1/CU).
__global__ __launch_bounds__(256) void weff_kernel(const float* __restrict__ E,
                                                   const float* __restrict__ g,
                                                   uint4* __restrict__ wt) {
  __shared__ float gs[NB * KEXP];
  int t = threadIdx.x;
  ((float2*)gs)[t] = ((const float2*)g)[t];
  int o = blockIdx.x * 16 + (t & 15);
  int i = blockIdx.y * 128 + (t >> 4) * 8;
  int b0 = blockIdx.z * 32;
  float e[8][8];
  #pragma unroll
  for (int k = 0; k < 8; ++k) {
    const float4* p = (const float4*)(E + (size_t)k * (COUT * CIN) + (size_t)o * CIN + i);
    float4 a = p[0], c = p[1];
    e[k][0] = a.x; e[k][1] = a.y; e[k][2] = a.z; e[k][3] = a.w;
    e[k][4] = c.x; e[k][5] = c.y; e[k][6] = c.z; e[k][7] = c.w;
  }
  __syncthreads();
  int base = ((o >> 8) * 16 + (i >> 5)) * 1024 + ((i >> 3) & 3) * 256 + (o & 255);
  for (int b = b0; b < b0 + 32; ++b) {
    float acc[8] = {0, 0, 0, 0, 0, 0, 0, 0};
    #pragma unroll
    for (int k = 0; k < 8; ++k) {
      float gv = gs[b * 8 + k];
      #pragma unroll
      for (int j = 0; j < 8; ++j) acc[j] += gv * e[k][j];
    }
    uint4 pk;
    pk.x = f2bf2(acc[0], acc[1]); pk.y = f2bf2(acc[2], acc[3]);
    pk.z = f2bf2(acc[4], acc[5]); pk.w = f2bf2(acc[6], acc[7]);
    wt[(size_t)base + (size_t)b * 32768] = pk;
  }
}

// ---------------- Kernel 4: batched GEMM, BM=256 x BN=112, BK=32 ----------
// Key insight: each weff A-unit is consumed by exactly ONE lane -> A loads
// global->VGPR directly (no LDS, no sharing needed); only B (256-fold reuse)
// goes through LDS (3-buffer ring, 21KB, glds w/ pre-swizzled source).
// Fully unrolled K-loop, depth-2 everywhere, counted vmcnt (never 0 mid-loop).
#define VMCNT(n) asm volatile("s_waitcnt vmcnt(" #n ")" ::: "memory")
__global__ __launch_bounds__(512) void gemm_kernel(const uint4* __restrict__ weff,
                                                   const uint4* __restrict__ xt,
                                                   float* __restrict__ out) {
  __shared__ uint4 ldsB[3][448];   // [kgrp4][col112] units, XOR-swizzled (21KB)
  int id = blockIdx.x;
  int xcd = id & 7, s = id >> 3;
  int bloc = s / 14, inner = s - bloc * 14;
  int b = xcd * 8 + bloc;
  int mb = inner & 1, nb = inner >> 1;

  int t = threadIdx.x;
  int lane = t & 63, w = t >> 6;          // 8 waves
  int l15 = lane & 15, l4 = lane >> 4;

  // A: this lane's two units per kk-slab: [kgrp=l4][row = w*32 + m*16 + l15]
  const uint4* asrc = weff + (size_t)b * 32768 + (size_t)mb * 16384
                      + l4 * 256 + w * 32 + l15;
  const uint4* bsrc = xt + (size_t)(b * 7 + nb) * 7168;

  // B glds: waves 0-6 fill slot s1; source pre-swizzled (involution).
  int s1 = w * 64 + lane, fs1 = s1 ^ ((s1 >> 3) & 7);

  f32x4 acc[2][7] = {};
  uint4 a[3][2];                           // 3 A reg-tiles in rotation

  // prologue: issue tiles 0 and 1
  #pragma unroll
  for (int p = 0; p < 2; ++p) {
    if (w < 7)
      __builtin_amdgcn_global_load_lds((GU32*)(bsrc + p * 448 + fs1),
                                       (LU32*)(&ldsB[p][s1]), 16, 0, 0);
    a[p][0] = asrc[p * 1024];
    a[p][1] = asrc[p * 1024 + 16];
  }
  if (w < 7) { VMCNT(3); } else { VMCNT(2); }   // B0+A0 landed; B1/A1 in flight

  #pragma unroll
  for (int kk = 0; kk < 16; ++kk) {
    __builtin_amdgcn_s_barrier();          // B(kk) visible to all waves
    __builtin_amdgcn_sched_barrier(0);

    if (kk < 14) {                         // issue tile kk+2 (depth-2)
      if (w < 7)
        __builtin_amdgcn_global_load_lds((GU32*)(bsrc + (kk + 2) * 448 + fs1),
                                         (LU32*)(&ldsB[(kk + 2) % 3][s1]), 16, 0, 0);
      a[(kk + 2) % 3][0] = asrc[(kk + 2) * 1024];
      a[(kk + 2) % 3][1] = asrc[(kk + 2) * 1024 + 16];
    }
    __builtin_amdgcn_sched_barrier(0);     // pin issues above compute

    bf16x8 af0 = __builtin_bit_cast(bf16x8, a[kk % 3][0]);
    bf16x8 af1 = __builtin_bit_cast(bf16x8, a[kk % 3][1]);
    #pragma unroll
    for (int u = 0; u < 7; ++u) {
      int un = l4 * 112 + u * 16 + l15;
      bf16x8 bf = *(const bf16x8*)&ldsB[kk % 3][un ^ ((un >> 3) & 7)];
      acc[0][u] = __builtin_amdgcn_mfma_f32_16x16x32_bf16(af0, bf, acc[0][u], 0, 0, 0);
      acc[1][u] = __builtin_amdgcn_mfma_f32_16x16x32_bf16(af1, bf, acc[1][u], 0, 0, 0);
    }

    // retire exactly {B(kk+1), A(kk+1)}; keep {B(kk+2), A(kk+2)} in flight
    if (kk < 14) {
      if (w < 7) { VMCNT(3); } else { VMCNT(2); }
    } else if (kk == 14) {
      VMCNT(0);                            // drain B15/A15 for the last tile
    }
    __builtin_amdgcn_sched_barrier(0);
  }

  // epilogue: D layout col=lane&15, row=(lane>>4)*4+reg
  int orow0 = mb * 256 + w * 32 + l4 * 4;
  int col = nb * 112 + l15;
  #pragma unroll
  for (int m = 0; m < 2; ++m) {
    #pragma unroll
    for (int u = 0; u < 7; ++u) {
      float* op = out + ((size_t)b * COUT + orow0 + m * 16) * HW + col + u * 16;
      #pragma unroll
      for (int r = 0; r < 4; ++r) op[(size_t)r * HW] = acc[m][u][r];
    }
  }
}

// ---------------- launcher -------------------------------------------------
extern "C" void kernel_launch(void* const* d_in, const int* in_sizes, int n_in,
                              void* d_out, int out_size, void* d_ws, size_t ws_size,
                              hipStream_t stream) {
  const float* x        = (const float*)d_in[0];
  const float* gate_w   = (const float*)d_in[1];
  const float* gate_b   = (const float*)d_in[2];
  const float* expert_w = (const float*)d_in[3];
  float* out = (float*)d_out;

  char* ws = (char*)d_ws;
  uint4* weff   = (uint4*)ws;                               // 33,554,432 B
  uint4* xt     = (uint4*)(ws + 33554432);                  // 51,380,224 B
  float* parts  = (float*)(ws + 33554432 + 51380224);       //    917,504 B
  float* g      = (float*)(ws + 33554432 + 51380224 + 917504);  //  2,048 B

  xtpool_kernel<<<7168, 256, 0, stream>>>(x, xt, parts);
  gate_kernel<<<NB, 256, 0, stream>>>(parts, gate_w, gate_b, g);
  weff_kernel<<<dim3(32, 4, 2), 256, 0, stream>>>(expert_w, g, weff);
  gemm_kernel<<<896, 512, 0, stream>>>(weff, xt, out);
}

// Round 11
// 92.705 us; speedup vs baseline: 1.0887x; 1.0887x over previous
//
#include <hip/hip_runtime.h>

// Problem constants: B=64, Cin=512, Cout=512, H=W=28 (HW=784), K=8 experts.
#define NB 64
#define CIN 512
#define COUT 512
#define HW 784
#define KEXP 8

typedef __attribute__((ext_vector_type(8))) short bf16x8;   // 8 bf16 = 4 VGPR (MFMA A/B frag)
typedef __attribute__((ext_vector_type(4))) float f32x4;    // MFMA C/D frag
typedef __attribute__((ext_vector_type(4))) unsigned int u32x4;

typedef const __attribute__((address_space(1))) unsigned int GU32;
typedef __attribute__((address_space(3))) unsigned int LU32;

__device__ __forceinline__ unsigned f2bf1(float f) {
  unsigned u = __builtin_bit_cast(unsigned, f);
  return (u + 0x7FFFu + ((u >> 16) & 1u)) >> 16;   // RNE fp32->bf16
}
__device__ __forceinline__ unsigned f2bf2(float lo, float hi) {
  return f2bf1(lo) | (f2bf1(hi) << 16);
}

// ---------------- Kernel 1: fused transpose(x)->bf16-tiled + pooled parts --
// (R8 version — scalar loads; R9's float4 variant was a ~2us regression.)
__global__ __launch_bounds__(256) void xtpool_kernel(const float* __restrict__ x,
                                                     uint4* __restrict__ xt,
                                                     float* __restrict__ parts) {
  __shared__ float tile[32][113];
  int id = blockIdx.x;
  int kk = id & 15, bn = id >> 4;
  int b = bn / 7, nb = bn - b * 7;
  const float* xsrc = x + (size_t)b * (CIN * HW) + (size_t)kk * 32 * HW + nb * 112;
  uint4* dst = xt + (size_t)id * 448;
  int t = threadIdx.x;

  #pragma unroll
  for (int i = 0; i < 14; ++i) {
    int idx = t + i * 256;                          // 0..3583
    int r = idx / 112, cc = idx - r * 112;
    tile[r][cc] = xsrc[(size_t)r * HW + cc];
  }
  __syncthreads();

  {
    int pr = t >> 3, pp = t & 7;
    float s = 0.f;
    #pragma unroll
    for (int i = 0; i < 14; ++i) s += tile[pr][pp * 14 + i];
    s += __shfl_xor(s, 1); s += __shfl_xor(s, 2); s += __shfl_xor(s, 4);
    if (pp == 0) parts[((size_t)nb * NB + b) * CIN + kk * 32 + pr] = s;
  }

  {
    int k0 = t / 112, c0 = t - k0 * 112;
    uint4 pk;
    pk.x = f2bf2(tile[k0 * 8 + 0][c0], tile[k0 * 8 + 1][c0]);
    pk.y = f2bf2(tile[k0 * 8 + 2][c0], tile[k0 * 8 + 3][c0]);
    pk.z = f2bf2(tile[k0 * 8 + 4][c0], tile[k0 * 8 + 5][c0]);
    pk.w = f2bf2(tile[k0 * 8 + 6][c0], tile[k0 * 8 + 7][c0]);
    dst[t] = pk;
  }
  if (t < 192) {
    int t2 = 256 + t, k1 = t2 / 112, c1 = t2 - k1 * 112;
    uint4 pk;
    pk.x = f2bf2(tile[k1 * 8 + 0][c1], tile[k1 * 8 + 1][c1]);
    pk.y = f2bf2(tile[k1 * 8 + 2][c1], tile[k1 * 8 + 3][c1]);
    pk.z = f2bf2(tile[k1 * 8 + 4][c1], tile[k1 * 8 + 5][c1]);
    pk.w = f2bf2(tile[k1 * 8 + 6][c1], tile[k1 * 8 + 7][c1]);
    dst[256 + t] = pk;
  }
}

// ---------------- Kernel 2: gate (per-batch block) + local sparsemax -------
__global__ __launch_bounds__(256) void gate_kernel(const float* __restrict__ parts,
                                                   const float* __restrict__ gw,
                                                   const float* __restrict__ gb,
                                                   float* __restrict__ g) {
  __shared__ float red[4][KEXP];
  int b = blockIdx.x;
  int t = threadIdx.x;
  int lane = t & 63, w = t >> 6;

  float p0 = 0.f, p1 = 0.f;
  #pragma unroll
  for (int q = 0; q < 7; ++q) {
    const float* pr = parts + (size_t)q * (NB * CIN) + b * CIN;
    p0 += pr[t];
    p1 += pr[t + 256];
  }
  float zk[KEXP];
  #pragma unroll
  for (int k = 0; k < KEXP; ++k)
    zk[k] = p0 * gw[k * CIN + t] + p1 * gw[k * CIN + t + 256];

  #pragma unroll
  for (int k = 0; k < KEXP; ++k) {
    float s = zk[k];
    #pragma unroll
    for (int off = 32; off; off >>= 1) s += __shfl_down(s, off);
    if (lane == 0) red[w][k] = s;
  }
  __syncthreads();

  if (t == 0) {
    float z[8], zs[8];
    #pragma unroll
    for (int j = 0; j < 8; ++j) {
      z[j] = (red[0][j] + red[1][j] + red[2][j] + red[3][j]) * (1.0f / 784.0f) + gb[j];
      zs[j] = z[j];
    }
    #pragma unroll
    for (int a = 1; a < 8; ++a) {
      float v = zs[a]; int j = a;
      while (j > 0 && zs[j - 1] < v) { zs[j] = zs[j - 1]; --j; }
      zs[j] = v;
    }
    float cums[8]; float csum = 0.f;
    #pragma unroll
    for (int j = 0; j < 8; ++j) { csum += zs[j]; cums[j] = csum; }
    int kz = 0;
    #pragma unroll
    for (int j = 0; j < 8; ++j)
      if (1.0f + (float)(j + 1) * zs[j] > cums[j]) kz = j + 1;
    float tau = (cums[kz - 1] - 1.0f) / (float)kz;
    #pragma unroll
    for (int j = 0; j < 8; ++j) g[b * 8 + j] = fmaxf(z[j] - tau, 0.0f);
  }
}

// ---------------- Kernel 3: w_eff builder (bf16, BM=256 GEMM-tiled) -------
__global__ __launch_bounds__(256) void weff_kernel(const float* __restrict__ E,
                                                   const float* __restrict__ g,
                                                   uint4* __restrict__ wt) {
  __shared__ float gs[NB * KEXP];
  int t = threadIdx.x;
  ((float2*)gs)[t] = ((const float2*)g)[t];
  int o = blockIdx.x * 16 + (t & 15);
  int i = blockIdx.y * 128 + (t >> 4) * 8;
  int b0 = blockIdx.z * 32;
  float e[8][8];
  #pragma unroll
  for (int k = 0; k < 8; ++k) {
    const float4* p = (const float4*)(E + (size_t)k * (COUT * CIN) + (size_t)o * CIN + i);
    float4 a = p[0], c = p[1];
    e[k][0] = a.x; e[k][1] = a.y; e[k][2] = a.z; e[k][3] = a.w;
    e[k][4] = c.x; e[k][5] = c.y; e[k][6] = c.z; e[k][7] = c.w;
  }
  __syncthreads();
  int base = ((o >> 8) * 16 + (i >> 5)) * 1024 + ((i >> 3) & 3) * 256 + (o & 255);
  for (int b = b0; b < b0 + 32; ++b) {
    float acc[8] = {0, 0, 0, 0, 0, 0, 0, 0};
    #pragma unroll
    for (int k = 0; k < 8; ++k) {
      float gv = gs[b * 8 + k];
      #pragma unroll
      for (int j = 0; j < 8; ++j) acc[j] += gv * e[k][j];
    }
    uint4 pk;
    pk.x = f2bf2(acc[0], acc[1]); pk.y = f2bf2(acc[2], acc[3]);
    pk.z = f2bf2(acc[4], acc[5]); pk.w = f2bf2(acc[6], acc[7]);
    wt[(size_t)base + (size_t)b * 32768] = pk;
  }
}

// ---------------- Kernel 4: batched GEMM, BM=256 x BN=112, BK=32 ----------
// A (no intra-block reuse) -> inline-asm global_load_dwordx4 to regs, 2-deep
// named ring; B (256-fold reuse) -> glds into 3-buffer LDS ring (21KB).
// ALL loop vmem manually counted (no compiler-tracked loads in the loop);
// the counted wait ties the A-regs as "+v" operands so MFMA data-depends on
// it (rule 18 without order-pinning). One sched_barrier after the barrier.
__global__ __launch_bounds__(512) void gemm_kernel(const uint4* __restrict__ weff,
                                                   const uint4* __restrict__ xt,
                                                   float* __restrict__ out) {
  __shared__ uint4 ldsB[3][448];   // [kgrp4][col112] units, XOR-swizzled
  int id = blockIdx.x;
  int xcd = id & 7, s = id >> 3;
  int bloc = s / 14, inner = s - bloc * 14;
  int b = xcd * 8 + bloc;
  int mb = inner & 1, nb = inner >> 1;

  int t = threadIdx.x;
  int lane = t & 63, w = t >> 6;          // 8 waves
  int l15 = lane & 15, l4 = lane >> 4;

  // A: this lane's two units per kk-slab: [kgrp=l4][row = w*32 + m*16 + l15]
  const uint4* asrc = weff + (size_t)b * 32768 + (size_t)mb * 16384
                      + l4 * 256 + w * 32 + l15;
  const uint4* bsrc = xt + (size_t)(b * 7 + nb) * 7168;

  int s1 = w * 64 + lane, fs1 = s1 ^ ((s1 >> 3) & 7);

  f32x4 acc[2][7] = {};
  u32x4 a[2][2];                           // 2-deep A reg ring (static idx)

#define LOADA(dst, kk, m)                                                     \
  asm volatile("global_load_dwordx4 %0, %1, off"                              \
               : "=v"(dst) : "v"((const void*)(asrc + (kk) * 1024 + (m) * 16)))
#define STAGEB(kk)                                                            \
  do { if (w < 7)                                                             \
    __builtin_amdgcn_global_load_lds((GU32*)(bsrc + (kk) * 448 + fs1),        \
                                     (LU32*)(&ldsB[(kk) % 3][s1]), 16, 0, 0); \
  } while (0)
  // counted wait; ties the tile's A regs so MFMA can't hoist above it
#define WAITTILE(n, x, y)                                                     \
  asm volatile("s_waitcnt vmcnt(" #n ")" : "+v"(x), "+v"(y) :: "memory")

  // prologue: tiles 0 and 1 in flight (per wave: 3 loads w<7, 2 loads w=7)
  STAGEB(0); LOADA(a[0][0], 0, 0); LOADA(a[0][1], 0, 1);
  STAGEB(1); LOADA(a[1][0], 1, 0); LOADA(a[1][1], 1, 1);

  #pragma unroll
  for (int kk = 0; kk < 16; ++kk) {
    // retire tile kk; keep tile kk+1 (3 loads w<7 / 2 loads w7) in flight
    if (kk < 15) {
      if (w < 7) { WAITTILE(3, a[kk & 1][0], a[kk & 1][1]); }
      else       { WAITTILE(2, a[kk & 1][0], a[kk & 1][1]); }
    } else {
      WAITTILE(0, a[kk & 1][0], a[kk & 1][1]);
    }
    __builtin_amdgcn_s_barrier();          // all waves' B(kk) visible
    __builtin_amdgcn_sched_barrier(0);

    bf16x8 af0 = __builtin_bit_cast(bf16x8, a[kk & 1][0]);
    bf16x8 af1 = __builtin_bit_cast(bf16x8, a[kk & 1][1]);
    #pragma unroll
    for (int u = 0; u < 7; ++u) {
      int un = l4 * 112 + u * 16 + l15;
      bf16x8 bf = *(const bf16x8*)&ldsB[kk % 3][un ^ ((un >> 3) & 7)];
      acc[0][u] = __builtin_amdgcn_mfma_f32_16x16x32_bf16(af0, bf, acc[0][u], 0, 0, 0);
      acc[1][u] = __builtin_amdgcn_mfma_f32_16x16x32_bf16(af1, bf, acc[1][u], 0, 0, 0);
    }

    // issue tile kk+2: ldsB[(kk+2)%3] is WAR-safe (its readers passed the
    // barrier at top of this iter); a[kk&1] reads happened above (anti-dep).
    if (kk < 14) {
      STAGEB(kk + 2);
      LOADA(a[kk & 1][0], kk + 2, 0);
      LOADA(a[kk & 1][1], kk + 2, 1);
    }
  }
#undef LOADA
#undef STAGEB
#undef WAITTILE

  // epilogue: D layout col=lane&15, row=(lane>>4)*4+reg
  int orow0 = mb * 256 + w * 32 + l4 * 4;
  int col = nb * 112 + l15;
  #pragma unroll
  for (int m = 0; m < 2; ++m) {
    #pragma unroll
    for (int u = 0; u < 7; ++u) {
      float* op = out + ((size_t)b * COUT + orow0 + m * 16) * HW + col + u * 16;
      #pragma unroll
      for (int r = 0; r < 4; ++r) op[(size_t)r * HW] = acc[m][u][r];
    }
  }
}

// ---------------- launcher -------------------------------------------------
extern "C" void kernel_launch(void* const* d_in, const int* in_sizes, int n_in,
                              void* d_out, int out_size, void* d_ws, size_t ws_size,
                              hipStream_t stream) {
  const float* x        = (const float*)d_in[0];
  const float* gate_w   = (const float*)d_in[1];
  const float* gate_b   = (const float*)d_in[2];
  const float* expert_w = (const float*)d_in[3];
  float* out = (float*)d_out;

  char* ws = (char*)d_ws;
  uint4* weff   = (uint4*)ws;                               // 33,554,432 B
  uint4* xt     = (uint4*)(ws + 33554432);                  // 51,380,224 B
  float* parts  = (float*)(ws + 33554432 + 51380224);       //    917,504 B
  float* g      = (float*)(ws + 33554432 + 51380224 + 917504);  //  2,048 B

  xtpool_kernel<<<7168, 256, 0, stream>>>(x, xt, parts);
  gate_kernel<<<NB, 256, 0, stream>>>(parts, gate_w, gate_b, g);
  weff_kernel<<<dim3(32, 4, 2), 256, 0, stream>>>(expert_w, g, weff);
  gemm_kernel<<<896, 512, 0, stream>>>(weff, xt, out);
}